// Round 8
// baseline (824.076 us; speedup 1.0000x reference)
//
#include <hip/hip_runtime.h>
#include <hip/hip_bf16.h>

#define C_ 256
#define H_ 256
#define V_ 10000
#define N_ 8
#define T_ 256
#define TM1_ 255
#define NB_ ((V_ + 31) / 32)
#define VT_ ((V_ + 31) / 32)
#define NCH_ 16                // chunks for the parallel scan

typedef _Float16 h2_t __attribute__((ext_vector_type(2)));
typedef _Float16 h4_t __attribute__((ext_vector_type(4)));
typedef _Float16 h8_t __attribute__((ext_vector_type(8)));
typedef float f4v __attribute__((ext_vector_type(4)));

// barrier with LDS-only drain (global loads/stores stay in flight)
__device__ __forceinline__ void bar_lgkm() {
  asm volatile("s_waitcnt lgkmcnt(0)\ns_barrier" ::: "memory");
}

__device__ __forceinline__ float wave_red_max(float v) {
#define DPP_MAX(ctrl) { int iv_ = __float_as_int(v); \
  int r_ = __builtin_amdgcn_update_dpp(iv_, iv_, ctrl, 0xF, 0xF, false); \
  v = fmaxf(v, __int_as_float(r_)); }
  DPP_MAX(0x111) DPP_MAX(0x112) DPP_MAX(0x114) DPP_MAX(0x118)
  DPP_MAX(0x142) DPP_MAX(0x143)
#undef DPP_MAX
  return __int_as_float(__builtin_amdgcn_readlane(__float_as_int(v), 63));
}
__device__ __forceinline__ float wave_red_sum(float v) {
#define DPP_ADD(ctrl) { \
  int r_ = __builtin_amdgcn_update_dpp(0, __float_as_int(v), ctrl, 0xF, 0xF, true); \
  v += __int_as_float(r_); }
  DPP_ADD(0x111) DPP_ADD(0x112) DPP_ADD(0x114) DPP_ADD(0x118)
  DPP_ADD(0x142) DPP_ADD(0x143)
#undef DPP_ADD
  return __int_as_float(__builtin_amdgcn_readlane(__float_as_int(v), 63));
}

__device__ __forceinline__ float block_allmax(float v, float* red) {
  v = wave_red_max(v);
  if ((threadIdx.x & 63) == 0) red[threadIdx.x >> 6] = v;
  __syncthreads();
  v = fmaxf(fmaxf(red[0], red[1]), fmaxf(red[2], red[3]));
  __syncthreads();
  return v;
}
__device__ __forceinline__ float block_allsum(float v, float* red) {
  v = wave_red_sum(v);
  if ((threadIdx.x & 63) == 0) red[threadIdx.x >> 6] = v;
  __syncthreads();
  v = (red[0] + red[1]) + (red[2] + red[3]);
  __syncthreads();
  return v;
}

// ---- w3 transpose ----
__global__ __launch_bounds__(256) void k_w3t(const float* __restrict__ w3,
                                             float* __restrict__ w3T) {
  __shared__ float t_s[32][33];
  const int tx = threadIdx.x & 31;
  const int ty = threadIdx.x >> 5;
  const int v0 = blockIdx.x * 32;
  const int k0 = blockIdx.y * 32;
#pragma unroll
  for (int r = 0; r < 4; ++r) {
    int k = k0 + ty + r * 8;
    int v = v0 + tx;
    if (v < V_) t_s[ty + r * 8][tx] = w3[k * V_ + v];
  }
  __syncthreads();
#pragma unroll
  for (int r = 0; r < 4; ++r) {
    int v = v0 + ty + r * 8;
    if (v < V_) w3T[(size_t)v * H_ + k0 + tx] = t_s[tx][ty + r * 8];
  }
}

// ---- residual MLP body ----
__device__ __forceinline__ void mlp4(
    const float* __restrict__ emb,
    const float* __restrict__ w1, const float* __restrict__ b1,
    const float* __restrict__ w2, const float* __restrict__ b2,
    int r0, float (&e_s)[4][C_], float (&h_s)[4][C_], float (&h2_s)[4][C_]) {
  const int tid = threadIdx.x;
#pragma unroll
  for (int rr = 0; rr < 4; ++rr)
    e_s[rr][tid] = emb[(r0 + rr) * H_ + tid];
  __syncthreads();
  float bb = b1[tid];
  float a0 = bb, a1 = bb, a2 = bb, a3 = bb;
  for (int k4 = 0; k4 < H_ / 4; ++k4) {
    float4 e0 = ((const float4*)e_s[0])[k4];
    float4 e1 = ((const float4*)e_s[1])[k4];
    float4 e2 = ((const float4*)e_s[2])[k4];
    float4 e3 = ((const float4*)e_s[3])[k4];
    const float* wp = w1 + (k4 * 4) * H_ + tid;
    float wa = wp[0], wb = wp[H_], wc = wp[2 * H_], wd = wp[3 * H_];
    a0 = fmaf(e0.x, wa, a0); a0 = fmaf(e0.y, wb, a0);
    a0 = fmaf(e0.z, wc, a0); a0 = fmaf(e0.w, wd, a0);
    a1 = fmaf(e1.x, wa, a1); a1 = fmaf(e1.y, wb, a1);
    a1 = fmaf(e1.z, wc, a1); a1 = fmaf(e1.w, wd, a1);
    a2 = fmaf(e2.x, wa, a2); a2 = fmaf(e2.y, wb, a2);
    a2 = fmaf(e2.z, wc, a2); a2 = fmaf(e2.w, wd, a2);
    a3 = fmaf(e3.x, wa, a3); a3 = fmaf(e3.y, wb, a3);
    a3 = fmaf(e3.z, wc, a3); a3 = fmaf(e3.w, wd, a3);
  }
  h_s[0][tid] = fmaxf(a0, 0.f);
  h_s[1][tid] = fmaxf(a1, 0.f);
  h_s[2][tid] = fmaxf(a2, 0.f);
  h_s[3][tid] = fmaxf(a3, 0.f);
  __syncthreads();
  bb = b2[tid];
  a0 = bb; a1 = bb; a2 = bb; a3 = bb;
  for (int k4 = 0; k4 < H_ / 4; ++k4) {
    float4 e0 = ((const float4*)h_s[0])[k4];
    float4 e1 = ((const float4*)h_s[1])[k4];
    float4 e2 = ((const float4*)h_s[2])[k4];
    float4 e3 = ((const float4*)h_s[3])[k4];
    const float* wp = w2 + (k4 * 4) * H_ + tid;
    float wa = wp[0], wb = wp[H_], wc = wp[2 * H_], wd = wp[3 * H_];
    a0 = fmaf(e0.x, wa, a0); a0 = fmaf(e0.y, wb, a0);
    a0 = fmaf(e0.z, wc, a0); a0 = fmaf(e0.w, wd, a0);
    a1 = fmaf(e1.x, wa, a1); a1 = fmaf(e1.y, wb, a1);
    a1 = fmaf(e1.z, wc, a1); a1 = fmaf(e1.w, wd, a1);
    a2 = fmaf(e2.x, wa, a2); a2 = fmaf(e2.y, wb, a2);
    a2 = fmaf(e2.z, wc, a2); a2 = fmaf(e2.w, wd, a2);
    a3 = fmaf(e3.x, wa, a3); a3 = fmaf(e3.y, wb, a3);
    a3 = fmaf(e3.z, wc, a3); a3 = fmaf(e3.w, wd, a3);
  }
  h2_s[0][tid] = fmaxf(a0, 0.f) + e_s[0][tid];
  h2_s[1][tid] = fmaxf(a1, 0.f) + e_s[1][tid];
  h2_s[2][tid] = fmaxf(a2, 0.f) + e_s[2][tid];
  h2_s[3][tid] = fmaxf(a3, 0.f) + e_s[3][tid];
  __syncthreads();
}

__global__ __launch_bounds__(256) void k_start(
    const float* __restrict__ emb, const float* __restrict__ w1,
    const float* __restrict__ b1, const float* __restrict__ w2,
    const float* __restrict__ b2, const float* __restrict__ w3,
    const float* __restrict__ b3, float* __restrict__ slogit) {
  __shared__ __align__(16) float e_s[4][C_], h_s[4][C_], h2_s[4][C_];
  __shared__ float red[4];
  const int r0 = blockIdx.x * 4;
  const int tid = threadIdx.x;
  mlp4(emb, w1, b1, w2, b2, r0, e_s, h_s, h2_s);
  float w3v = w3[tid];
  float s0 = block_allsum(h2_s[0][tid] * w3v, red);
  float s1 = block_allsum(h2_s[1][tid] * w3v, red);
  float s2 = block_allsum(h2_s[2][tid] * w3v, red);
  float s3 = block_allsum(h2_s[3][tid] * w3v, red);
  if (tid == 0) {
    float bb = b3[0];
    slogit[r0 + 0] = s0 + bb;
    slogit[r0 + 1] = s1 + bb;
    slogit[r0 + 2] = s2 + bb;
    slogit[r0 + 3] = s3 + bb;
  }
}

__global__ void k_init(const float* __restrict__ slogit, float* __restrict__ initv) {
  __shared__ float red[4];
  const int tid = threadIdx.x;
  float x = slogit[tid];
  float m = block_allmax(x, red);
  float se = block_allsum(__expf(x - m), red);
  initv[tid] = x - m - __logf(se);
}

__global__ __launch_bounds__(256) void k_trans(
    const float* __restrict__ emb, const float* __restrict__ w1,
    const float* __restrict__ b1, const float* __restrict__ w2,
    const float* __restrict__ b2, const float* __restrict__ w3,
    const float* __restrict__ b3, float* __restrict__ Pf,
    float* __restrict__ PLf, float* __restrict__ PTf,
    _Float16* __restrict__ P_h, _Float16* __restrict__ PT_h) {
  __shared__ __align__(16) float e_s[4][C_], h_s[4][C_], h2_s[4][C_];
  __shared__ float red[4];
  const int r0 = blockIdx.x * 4;
  const int tid = threadIdx.x;
  mlp4(emb, w1, b1, w2, b2, r0, e_s, h_s, h2_s);
  float lb = b3[tid];
  float l0 = lb, l1 = lb, l2 = lb, l3 = lb;
  for (int k4 = 0; k4 < H_ / 4; ++k4) {
    float4 e0 = ((const float4*)h2_s[0])[k4];
    float4 e1 = ((const float4*)h2_s[1])[k4];
    float4 e2 = ((const float4*)h2_s[2])[k4];
    float4 e3 = ((const float4*)h2_s[3])[k4];
    const float* wp = w3 + (k4 * 4) * C_ + tid;
    float wa = wp[0], wb = wp[C_], wc = wp[2 * C_], wd = wp[3 * C_];
    l0 = fmaf(e0.x, wa, l0); l0 = fmaf(e0.y, wb, l0);
    l0 = fmaf(e0.z, wc, l0); l0 = fmaf(e0.w, wd, l0);
    l1 = fmaf(e1.x, wa, l1); l1 = fmaf(e1.y, wb, l1);
    l1 = fmaf(e1.z, wc, l1); l1 = fmaf(e1.w, wd, l1);
    l2 = fmaf(e2.x, wa, l2); l2 = fmaf(e2.y, wb, l2);
    l2 = fmaf(e2.z, wc, l2); l2 = fmaf(e2.w, wd, l2);
    l3 = fmaf(e3.x, wa, l3); l3 = fmaf(e3.y, wb, l3);
    l3 = fmaf(e3.z, wc, l3); l3 = fmaf(e3.w, wd, l3);
  }
  float lg[4] = {l0, l1, l2, l3};
#pragma unroll
  for (int rr = 0; rr < 4; ++rr) {
    float m = block_allmax(lg[rr], red);
    float e = __expf(lg[rr] - m);
    float se = block_allsum(e, red);
    float p = e / se;
    float tv = lg[rr] - m - __logf(se);
    const int r = r0 + rr;
    Pf[r * C_ + tid] = p;
    PLf[r * C_ + tid] = p * tv;
    PTf[tid * C_ + r] = p;
    P_h[r * C_ + tid] = (_Float16)p;
    PT_h[tid * C_ + r] = (_Float16)p;
  }
}

__global__ __launch_bounds__(256) void k_term_mlp(
    const float* __restrict__ emb, const float* __restrict__ w1,
    const float* __restrict__ b1, const float* __restrict__ w2,
    const float* __restrict__ b2, float* __restrict__ H2,
    float* __restrict__ H2T) {
  __shared__ __align__(16) float e_s[4][C_], h_s[4][C_], h2_s[4][C_];
  const int r0 = blockIdx.x * 4;
  const int tid = threadIdx.x;
  mlp4(emb, w1, b1, w2, b2, r0, e_s, h_s, h2_s);
#pragma unroll
  for (int rr = 0; rr < 4; ++rr) {
    const int r = r0 + rr;
    float v = h2_s[rr][tid];
    H2[r * H_ + tid] = v;
    H2T[tid * C_ + r] = v;
  }
}

__global__ __launch_bounds__(256) void k_term_stats(
    const float* __restrict__ H2, const float* __restrict__ w3,
    const float* __restrict__ b3, float* __restrict__ partm,
    float* __restrict__ parts) {
  __shared__ __align__(16) float w3_s[H_][32];
  __shared__ float b3_s[32];
  const int v0 = blockIdx.x * 32;
  const int tid = threadIdx.x;
  const int ncols = min(32, V_ - v0);
  for (int idx = tid; idx < H_ * 32; idx += 256) {
    int k = idx >> 5, c = idx & 31;
    w3_s[k][c] = (c < ncols) ? w3[k * V_ + v0 + c] : 0.f;
  }
  if (tid < 32) b3_s[tid] = (tid < ncols) ? b3[v0 + tid] : 0.f;
  __syncthreads();
  float acc[32];
#pragma unroll
  for (int c = 0; c < 32; ++c) acc[c] = 0.f;
  const float4* hq = (const float4*)(H2 + tid * H_);
  for (int k4 = 0; k4 < H_ / 4; ++k4) {
    float4 h = hq[k4];
    float hk[4];
    *(float4*)hk = h;
#pragma unroll
    for (int kk = 0; kk < 4; ++kk) {
      float hv = hk[kk];
      const int k = k4 * 4 + kk;
      const float4* wq = (const float4*)(&w3_s[k][0]);
#pragma unroll
      for (int c4 = 0; c4 < 8; ++c4) {
        float4 w = wq[c4];
        acc[c4 * 4 + 0] = fmaf(hv, w.x, acc[c4 * 4 + 0]);
        acc[c4 * 4 + 1] = fmaf(hv, w.y, acc[c4 * 4 + 1]);
        acc[c4 * 4 + 2] = fmaf(hv, w.z, acc[c4 * 4 + 2]);
        acc[c4 * 4 + 3] = fmaf(hv, w.w, acc[c4 * 4 + 3]);
      }
    }
  }
  float m = -1e30f;
#pragma unroll
  for (int c = 0; c < 32; ++c) {
    acc[c] += b3_s[c];
    if (c < ncols) m = fmaxf(m, acc[c]);
  }
  float se = 0.f;
#pragma unroll
  for (int c = 0; c < 32; ++c)
    if (c < ncols) se += __expf(acc[c] - m);
  partm[blockIdx.x * C_ + tid] = m;
  parts[blockIdx.x * C_ + tid] = se;
}

__global__ void k_denom(const float* __restrict__ partm,
                        const float* __restrict__ parts,
                        float* __restrict__ denom) {
  const int r = threadIdx.x;
  float m = -1e30f;
#pragma unroll 8
  for (int b = 0; b < NB_; ++b) m = fmaxf(m, partm[b * C_ + r]);
  float s = 0.f;
#pragma unroll 8
  for (int b = 0; b < NB_; ++b)
    s += parts[b * C_ + r] * __expf(partm[b * C_ + r] - m);
  denom[r] = m + __logf(s);
}

// ---- emissions via w3T (coalesced) ----
__global__ __launch_bounds__(256) void k_obs3(
    const int* __restrict__ text, const float* __restrict__ H2T,
    const float* __restrict__ w3T, const float* __restrict__ b3,
    const float* __restrict__ denom, float* __restrict__ EOBS,
    float* __restrict__ Karr) {
  __shared__ __align__(16) float w_s[H_][8];
  __shared__ float redm[4][8];
  const int c = threadIdx.x;
  const int wid = c >> 6;
  const int lane = c & 63;
  const int base = blockIdx.x * 8;
  int tok[8];
#pragma unroll
  for (int i = 0; i < 8; ++i) tok[i] = text[base + i];
  float wtmp[8];
#pragma unroll
  for (int i = 0; i < 8; ++i) wtmp[i] = w3T[(size_t)tok[i] * H_ + c];
  float b3t[8];
#pragma unroll
  for (int i = 0; i < 8; ++i) b3t[i] = b3[tok[i]];
#pragma unroll
  for (int i = 0; i < 8; ++i) w_s[c][i] = wtmp[i];
  __syncthreads();
  float acc[8];
#pragma unroll
  for (int i = 0; i < 8; ++i) acc[i] = 0.f;
  for (int k4 = 0; k4 < H_ / 4; ++k4) {
    float hv[4];
#pragma unroll
    for (int kk = 0; kk < 4; ++kk) hv[kk] = H2T[(k4 * 4 + kk) * C_ + c];
#pragma unroll
    for (int kk = 0; kk < 4; ++kk) {
      const float4* wq = (const float4*)(&w_s[k4 * 4 + kk][0]);
      float4 wa = wq[0], wb = wq[1];
      acc[0] = fmaf(hv[kk], wa.x, acc[0]);
      acc[1] = fmaf(hv[kk], wa.y, acc[1]);
      acc[2] = fmaf(hv[kk], wa.z, acc[2]);
      acc[3] = fmaf(hv[kk], wa.w, acc[3]);
      acc[4] = fmaf(hv[kk], wb.x, acc[4]);
      acc[5] = fmaf(hv[kk], wb.y, acc[5]);
      acc[6] = fmaf(hv[kk], wb.z, acc[6]);
      acc[7] = fmaf(hv[kk], wb.w, acc[7]);
    }
  }
  float dn = denom[c];
  float obsv[8];
#pragma unroll
  for (int i = 0; i < 8; ++i) obsv[i] = acc[i] + b3t[i] - dn;
#pragma unroll
  for (int i = 0; i < 8; ++i) {
    float wm = wave_red_max(obsv[i]);
    if (lane == 0) redm[wid][i] = wm;
  }
  __syncthreads();
#pragma unroll
  for (int i = 0; i < 8; ++i) {
    float Ki = fmaxf(fmaxf(redm[0][i], redm[1][i]),
                     fmaxf(redm[2][i], redm[3][i]));
    EOBS[(base + i) * C_ + c] = __expf(obsv[i] - Ki);
    if (c == 0) Karr[base + i] = Ki;
  }
}

// ============ Phase A: per-chunk matrix products =============
// fwd: M_j = prod_{e=16j+16..16j+1} diag(eo_e)P  (built left-multiplying)
// bwd: M_j = prod_{t=238-16j..253-16j} P^T diag(eo_{t+2})
// LDS stores Mt[a][b] = M[b][a] (f16). Delayed scalar rescale, off accumulates.
__global__ __launch_bounds__(256, 1) void k_chA(
    const _Float16* __restrict__ P_h, const _Float16* __restrict__ PT_h,
    const float* __restrict__ EOBS, _Float16* __restrict__ MtG,
    float* __restrict__ OffG) {
  __shared__ __align__(16) _Float16 Mt[C_][C_];   // 128 KB
  __shared__ __align__(16) float eo_s[16][C_];    // 16 KB
  __shared__ float red[4];
  const int j = blockIdx.x;   // chunk 0..14
  const int n = blockIdx.y;
  const int d = blockIdx.z;   // 0 fwd, 1 bwd
  const int tid = threadIdx.x;
  const int wave = tid >> 6, lane = tid & 63, quad = lane >> 4, nn16 = lane & 15;
  const int len = 16;         // j<=14 chunks are full
  for (int i = 0; i < len; ++i) {
    int e = d ? (255 - 16 * j - i) : (16 * j + 1 + i);
    eo_s[i][tid] = EOBS[((size_t)n * T_ + e) * C_ + tid];
  }
  __syncthreads();
  // init Mt = S_first^T layout:
  // fwd: Mt[n'][k] = PT_h[n'][k] * eo0[k] ; bwd: Mt[n'][k] = P_h[n'][k] * eo0[n']
  float lmx = 0.f;
  {
    const _Float16* src = (d ? P_h : PT_h) + (size_t)tid * C_;
    float rowscale = eo_s[0][tid];
    for (int k8 = 0; k8 < 32; ++k8) {
      h8_t v = *(const h8_t*)(src + k8 * 8);
      h8_t o;
#pragma unroll
      for (int q = 0; q < 8; ++q) {
        float f = (float)v[q] * (d ? rowscale : eo_s[0][k8 * 8 + q]);
        lmx = fmaxf(lmx, f);
        o[q] = (_Float16)f;
      }
      *(h8_t*)(&Mt[tid][k8 * 8]) = o;
    }
  }
  {
    float wm = wave_red_max(lmx);
    if (lane == 0) red[wave] = wm;
  }
  bar_lgkm();
  float a = fmaxf(fmaxf(fmaxf(red[0], red[1]), fmaxf(red[2], red[3])), 1e-30f);
  float off = 0.f;
  // A-frags: fwd A=P, bwd A=P^T
  const _Float16* Ab = d ? PT_h : P_h;
  h8_t afrag[4][8];
#pragma unroll
  for (int mt = 0; mt < 4; ++mt) {
    const _Float16* rp = Ab + (size_t)((wave << 6) + (mt << 4) + nn16) * C_ + (quad << 3);
#pragma unroll
    for (int kt = 0; kt < 8; ++kt) afrag[mt][kt] = *(const h8_t*)(rp + (kt << 5));
  }
#pragma unroll 1
  for (int i = 1; i < len; ++i) {
    float invs = 1.f / a;
    off += __logf(a);
    lmx = 0.f;
    f4v eoRow[4];
    h8_t eof[8];
    if (!d) {
#pragma unroll
      for (int mt = 0; mt < 4; ++mt)
        eoRow[mt] = *(const f4v*)(&eo_s[i][(wave << 6) + (mt << 4) + (quad << 2)]);
    } else {
#pragma unroll
      for (int kt = 0; kt < 8; ++kt) {
        h8_t t;
#pragma unroll
        for (int q = 0; q < 8; ++q) t[q] = (_Float16)eo_s[i][(kt << 5) + (quad << 3) + q];
        eof[kt] = t;
      }
    }
#pragma unroll 1
    for (int nb = 0; nb < 16; ++nb) {
      h8_t bf[8];
#pragma unroll
      for (int kt = 0; kt < 8; ++kt) {
        h8_t b = *(const h8_t*)(&Mt[(nb << 4) + nn16][(kt << 5) + (quad << 3)]);
        bf[kt] = d ? (h8_t)(b * eof[kt]) : b;
      }
      f4v acc[4];
#pragma unroll
      for (int mt = 0; mt < 4; ++mt) acc[mt] = (f4v){0.f, 0.f, 0.f, 0.f};
#pragma unroll
      for (int kt = 0; kt < 8; ++kt)
#pragma unroll
        for (int mt = 0; mt < 4; ++mt)
          acc[mt] = __builtin_amdgcn_mfma_f32_16x16x32_f16(afrag[mt][kt], bf[kt], acc[mt], 0, 0, 0);
      h4_t wv[4];
#pragma unroll
      for (int mt = 0; mt < 4; ++mt) {
#pragma unroll
        for (int r = 0; r < 4; ++r) {
          float f = acc[mt][r] * invs * (d ? 1.f : eoRow[mt][r]);
          lmx = fmaxf(lmx, f);
          wv[mt][r] = (_Float16)f;
        }
      }
      bar_lgkm();   // all reads of Mt rows nb done
#pragma unroll
      for (int mt = 0; mt < 4; ++mt)
        *(h4_t*)(&Mt[(nb << 4) + nn16][(wave << 6) + (mt << 4) + (quad << 2)]) = wv[mt];
    }
    float wm = wave_red_max(lmx);
    if (lane == 0) red[wave] = wm;
    bar_lgkm();   // iteration boundary
    a = fmaxf(fmaxf(fmaxf(red[0], red[1]), fmaxf(red[2], red[3])), 1e-30f);
  }
  // copy out
  _Float16* dst = MtG + (((size_t)d * 8 + n) * NCH_ + j) * (C_ * C_);
  const h8_t* s8 = (const h8_t*)&Mt[0][0];
  h8_t* d8 = (h8_t*)dst;
  for (int i = 0; i < 32; ++i) d8[i * 256 + tid] = s8[i * 256 + tid];
  if (tid == 0) OffG[((size_t)d * 8 + n) * NCH_ + j] = off;
}

// ============ Phase B: boundary vectors =============
// BND[d][j][n][c] = boundary vec (normalized), BOF = log offset
// fwd: bnd[j] = alpha_{16j}; bwd: bnd[j] = beta_{254-16j}
__global__ __launch_bounds__(256) void k_chB(
    const _Float16* __restrict__ MtG, const float* __restrict__ OffG,
    const float* __restrict__ initv, const float* __restrict__ EOBS,
    const float* __restrict__ Karr, float* __restrict__ BND,
    float* __restrict__ BOF) {
  __shared__ float b_s[C_];
  __shared__ float red[4];
  const int n = blockIdx.x, d = blockIdx.y;
  const int tid = threadIdx.x;
  float b, boff;
  if (d == 0) {
    float x0 = initv[tid] + __logf(EOBS[(size_t)(n * T_) * C_ + tid]) + Karr[n * T_];
    float m0 = block_allmax(x0, red);
    b = __expf(x0 - m0);
    boff = m0;
  } else {
    b = 1.f;
    boff = 0.f;
  }
  const size_t base = ((size_t)d * 8 + n) * NCH_;
  BND[(base + 0) * C_ + tid] = b;
  if (tid == 0) BOF[base + 0] = boff;
#pragma unroll 1
  for (int j = 0; j < 15; ++j) {
    b_s[tid] = b;
    __syncthreads();
    const _Float16* M = MtG + (base + j) * (C_ * C_);
    float acc = 0.f;
#pragma unroll 1
    for (int k = 0; k < C_; k += 8) {
      float m0 = (float)M[(size_t)(k + 0) * C_ + tid];
      float m1 = (float)M[(size_t)(k + 1) * C_ + tid];
      float m2 = (float)M[(size_t)(k + 2) * C_ + tid];
      float m3 = (float)M[(size_t)(k + 3) * C_ + tid];
      float m4 = (float)M[(size_t)(k + 4) * C_ + tid];
      float m5 = (float)M[(size_t)(k + 5) * C_ + tid];
      float m6 = (float)M[(size_t)(k + 6) * C_ + tid];
      float m7 = (float)M[(size_t)(k + 7) * C_ + tid];
      acc = fmaf(m0, b_s[k + 0], acc);
      acc = fmaf(m1, b_s[k + 1], acc);
      acc = fmaf(m2, b_s[k + 2], acc);
      acc = fmaf(m3, b_s[k + 3], acc);
      acc = fmaf(m4, b_s[k + 4], acc);
      acc = fmaf(m5, b_s[k + 5], acc);
      acc = fmaf(m6, b_s[k + 6], acc);
      acc = fmaf(m7, b_s[k + 7], acc);
    }
    float s = block_allmax(acc, red);
    s = fmaxf(s, 1e-30f);
    b = acc / s;
    float ks = 0.f;
    for (int i = 0; i < 16; ++i) {
      int e = d ? (255 - 16 * j - i) : (16 * j + 1 + i);
      ks += Karr[n * T_ + e];
    }
    boff += OffG[base + j] + __logf(s) + ks;
    BND[(base + j + 1) * C_ + tid] = b;
    if (tid == 0) BOF[base + j + 1] = boff;
  }
}

// ============ Phase C: within-chunk replay (proven MFMA matvec) =============
__global__ __launch_bounds__(256, 1) void k_chC(
    const _Float16* __restrict__ P_h, const _Float16* __restrict__ PT_h,
    const float* __restrict__ EOBS, const float* __restrict__ Karr,
    const float* __restrict__ BND, const float* __restrict__ BOF,
    float* __restrict__ AL, float* __restrict__ BL, float* __restrict__ CC,
    float* __restrict__ DD, float* __restrict__ LOGZ) {
  __shared__ __align__(16) _Float16 ubuf[C_];
  __shared__ __align__(16) float eo_s[16][C_];
  __shared__ float Ksm[16];
  __shared__ float red[4];
  const int j = blockIdx.x;   // 0..15
  const int n = blockIdx.y;
  const int d = blockIdx.z;
  const int tid = threadIdx.x;
  const int wave = tid >> 6, lane = tid & 63, quad = lane >> 4, nn16 = lane & 15;
  const int len = d ? ((j == 15) ? 14 : 16) : ((j == 15) ? 15 : 16);
  for (int i = 0; i < len; ++i) {
    int e = d ? (255 - 16 * j - i) : (16 * j + 1 + i);
    eo_s[i][tid] = EOBS[((size_t)n * T_ + e) * C_ + tid];
  }
  if (tid < len) {
    int e = d ? (255 - 16 * j - tid) : (16 * j + 1 + tid);
    Ksm[tid] = Karr[n * T_ + e];
  }
  const _Float16* M = d ? PT_h : P_h;
  h8_t afrag[4][8];
#pragma unroll
  for (int mt = 0; mt < 4; ++mt) {
    const _Float16* rp = M + (size_t)((wave << 6) + (mt << 4) + nn16) * C_ + (quad << 3);
#pragma unroll
    for (int kt = 0; kt < 8; ++kt) afrag[mt][kt] = *(const h8_t*)(rp + (kt << 5));
  }
  const int stb = (wave << 6) + (quad << 2);
  const size_t base = ((size_t)d * 8 + n) * NCH_ + j;
  f4v v[4];
  {
    const float* bp = BND + base * C_;
#pragma unroll
    for (int mt = 0; mt < 4; ++mt) v[mt] = *(const f4v*)(bp + stb + (mt << 4));
  }
  float off = BOF[base];
  __syncthreads();   // eo_s / Ksm visible

  if (d == 0) {
    if (j == 0) {
      if (nn16 == 0) {
#pragma unroll
        for (int mt = 0; mt < 4; ++mt)
          *(f4v*)(AL + (size_t)(0 * N_ + n) * C_ + stb + (mt << 4)) = v[mt];
      }
      if (tid == 0) CC[0 * N_ + n] = off;
    }
    if (nn16 == 0) {
#pragma unroll
      for (int mt = 0; mt < 4; ++mt) {
        h4_t p;
#pragma unroll
        for (int r = 0; r < 4; ++r) p[r] = (_Float16)v[mt][r];
        *(h4_t*)(&ubuf[stb + (mt << 4)]) = p;
      }
    }
    bar_lgkm();
#pragma unroll 1
    for (int i = 0; i < len; ++i) {
      const int e = 16 * j + 1 + i;
      h8_t bf[8];
#pragma unroll
      for (int kt = 0; kt < 8; ++kt)
        bf[kt] = *(const h8_t*)(&ubuf[(kt << 5) + (quad << 3)]);
      f4v acc[4];
#pragma unroll
      for (int mt = 0; mt < 4; ++mt) acc[mt] = (f4v){0.f, 0.f, 0.f, 0.f};
#pragma unroll
      for (int kt = 0; kt < 8; ++kt)
#pragma unroll
        for (int mt = 0; mt < 4; ++mt)
          acc[mt] = __builtin_amdgcn_mfma_f32_16x16x32_f16(afrag[mt][kt], bf[kt], acc[mt], 0, 0, 0);
      float lmx = -1e30f;
#pragma unroll
      for (int mt = 0; mt < 4; ++mt) {
        f4v eoR = *(const f4v*)(&eo_s[i][stb + (mt << 4)]);
#pragma unroll
        for (int r = 0; r < 4; ++r) {
          v[mt][r] = acc[mt][r] * eoR[r];
          lmx = fmaxf(lmx, v[mt][r]);
        }
      }
      float wm = wave_red_max(lmx);
      if (lane == 0) red[wave] = wm;
      bar_lgkm();   // red visible; all ubuf reads done
      float m = fmaxf(fmaxf(fmaxf(red[0], red[1]), fmaxf(red[2], red[3])), 1e-30f);
      float invm = 1.f / m;
      off += Ksm[i] + __logf(m);
#pragma unroll
      for (int mt = 0; mt < 4; ++mt)
#pragma unroll
        for (int r = 0; r < 4; ++r) v[mt][r] *= invm;
      if (nn16 == 0) {
#pragma unroll
        for (int mt = 0; mt < 4; ++mt) {
          h4_t p;
#pragma unroll
          for (int r = 0; r < 4; ++r) p[r] = (_Float16)v[mt][r];
          *(h4_t*)(&ubuf[stb + (mt << 4)]) = p;
          *(f4v*)(AL + (size_t)(e * N_ + n) * C_ + stb + (mt << 4)) = v[mt];
        }
      }
      if (tid == 0) CC[e * N_ + n] = off;
      bar_lgkm();
    }
    if (j == 15) {
      float s = 0.f;
#pragma unroll
      for (int mt = 0; mt < 4; ++mt)
        s += (v[mt][0] + v[mt][1]) + (v[mt][2] + v[mt][3]);
      s = wave_red_sum(s);
      if (lane == 0) red[wave] = s;
      __syncthreads();
      if (tid == 0) {
        float S = ((red[0] + red[1]) + (red[2] + red[3])) * (1.f / 16.f);
        LOGZ[n] = __logf(S) + off;
      }
    }
  } else {
    if (j == 0) {
      if (nn16 == 0) {
        f4v one = (f4v){1.f, 1.f, 1.f, 1.f};
#pragma unroll
        for (int mt = 0; mt < 4; ++mt)
          *(f4v*)(BL + (size_t)(254 * N_ + n) * C_ + stb + (mt << 4)) = one;
      }
      if (tid == 0) DD[254 * N_ + n] = 0.f;
    }
#pragma unroll 1
    for (int i = 0; i < len; ++i) {
      const int t = 253 - 16 * j - i;
      if (nn16 == 0) {
#pragma unroll
        for (int mt = 0; mt < 4; ++mt) {
          f4v eoR = *(const f4v*)(&eo_s[i][stb + (mt << 4)]);
          h4_t p;
#pragma unroll
          for (int r = 0; r < 4; ++r) p[r] = (_Float16)(v[mt][r] * eoR[r]);
          *(h4_t*)(&ubuf[stb + (mt << 4)]) = p;
        }
      }
      bar_lgkm();
      h8_t bf[8];
#pragma unroll
      for (int kt = 0; kt < 8; ++kt)
        bf[kt] = *(const h8_t*)(&ubuf[(kt << 5) + (quad << 3)]);
      f4v acc[4];
#pragma unroll
      for (int mt = 0; mt < 4; ++mt) acc[mt] = (f4v){0.f, 0.f, 0.f, 0.f};
#pragma unroll
      for (int kt = 0; kt < 8; ++kt)
#pragma unroll
        for (int mt = 0; mt < 4; ++mt)
          acc[mt] = __builtin_amdgcn_mfma_f32_16x16x32_f16(afrag[mt][kt], bf[kt], acc[mt], 0, 0, 0);
      float lmx = -1e30f;
#pragma unroll
      for (int mt = 0; mt < 4; ++mt)
#pragma unroll
        for (int r = 0; r < 4; ++r) lmx = fmaxf(lmx, acc[mt][r]);
      float wm = wave_red_max(lmx);
      if (lane == 0) red[wave] = wm;
      bar_lgkm();   // red + ubuf reads done
      float m = fmaxf(fmaxf(fmaxf(red[0], red[1]), fmaxf(red[2], red[3])), 1e-30f);
      float invm = 1.f / m;
      off += Ksm[i] + __logf(m);
#pragma unroll
      for (int mt = 0; mt < 4; ++mt) {
#pragma unroll
        for (int r = 0; r < 4; ++r) v[mt][r] = acc[mt][r] * invm;
        if (nn16 == 0)
          *(f4v*)(BL + (size_t)(t * N_ + n) * C_ + stb + (mt << 4)) = v[mt];
      }
      if (tid == 0) DD[t * N_ + n] = off;
    }
  }
}

// ---- elbo, split over 2 sequence groups (+ fused evidence) ----
#define NH_ 4
__global__ __launch_bounds__(256) void k_elbo(
    const float* __restrict__ Pf, const float* __restrict__ PLf,
    const float* __restrict__ PTf, const float* __restrict__ AL,
    const float* __restrict__ BL, const float* __restrict__ CC,
    const float* __restrict__ DD, const float* __restrict__ EOBS,
    const float* __restrict__ Karr, const float* __restrict__ LOGZ,
    float* __restrict__ out) {
  __shared__ __align__(16) float A_s[NH_][C_];
  __shared__ __align__(16) float B_s[NH_][C_];
  __shared__ float red[4];
  const int t = blockIdx.x;
  const int nb = blockIdx.y * NH_;
  const int c = threadIdx.x;
  if (t == 0 && blockIdx.y == 0 && c == 0) {
    float s = 0.f;
#pragma unroll
    for (int nn = 0; nn < N_; ++nn) s += LOGZ[nn];
    out[1] = s;
  }
  float sc[NH_], Kv[NH_], cc[NH_];
#pragma unroll
  for (int nn = 0; nn < NH_; ++nn) {
    const int n = nb + nn;
    A_s[nn][c] = AL[(t * N_ + n) * C_ + c];
    Kv[nn] = Karr[n * T_ + t + 1];
    cc[nn] = CC[t * N_ + n];
    sc[nn] = __expf(cc[nn] + DD[t * N_ + n] + Kv[nn] - LOGZ[n]);
  }
  __syncthreads();
  float accPA[NH_], accPL[NH_];
#pragma unroll
  for (int nn = 0; nn < NH_; ++nn) { accPA[nn] = 0.f; accPL[nn] = 0.f; }
  const float4* pr = (const float4*)(Pf + c * C_);
  const float4* plr = (const float4*)(PLf + c * C_);
  for (int j = 0; j < C_ / 4; ++j) {
    float4 p = pr[j];
    float4 pl = plr[j];
#pragma unroll
    for (int nn = 0; nn < NH_; ++nn) {
      float4 a = ((const float4*)A_s[nn])[j];
      accPA[nn] += p.x * a.x + p.y * a.y + p.z * a.z + p.w * a.w;
      accPL[nn] += pl.x * a.x + pl.y * a.y + pl.z * a.z + pl.w * a.w;
    }
  }
  float contrib = 0.f;
  float Bv[NH_];
#pragma unroll
  for (int nn = 0; nn < NH_; ++nn) {
    const int n = nb + nn;
    float eo = EOBS[(n * T_ + t + 1) * C_ + c];
    float ob = __logf(eo) + Kv[nn];
    float B = eo * BL[(t * N_ + n) * C_ + c] * sc[nn];
    Bv[nn] = B;
    contrib += B * fmaf(ob, accPA[nn], accPL[nn]);
  }
  if (t == 0) {
#pragma unroll
    for (int nn = 0; nn < NH_; ++nn) B_s[nn][c] = Bv[nn];
    __syncthreads();
    const float4* ptq = (const float4*)(PTf + c * C_);
    float accPT[NH_];
#pragma unroll
    for (int nn = 0; nn < NH_; ++nn) accPT[nn] = 0.f;
    for (int j = 0; j < C_ / 4; ++j) {
      float4 p = ptq[j];
#pragma unroll
      for (int nn = 0; nn < NH_; ++nn) {
        float4 b = ((const float4*)B_s[nn])[j];
        accPT[nn] += p.x * b.x + p.y * b.y + p.z * b.z + p.w * b.w;
      }
    }
#pragma unroll
    for (int nn = 0; nn < NH_; ++nn) {
      float a0v = A_s[nn][c];
      if (a0v > 0.f)
        contrib += a0v * (__logf(a0v) + cc[nn]) * accPT[nn];
    }
  }
  contrib = wave_red_sum(contrib);
  if ((c & 63) == 0) red[c >> 6] = contrib;
  __syncthreads();
  if (c == 0) atomicAdd(out, (red[0] + red[1]) + (red[2] + red[3]));
}

extern "C" void kernel_launch(void* const* d_in, const int* in_sizes, int n_in,
                              void* d_out, int out_size, void* d_ws, size_t ws_size,
                              hipStream_t stream) {
  (void)in_sizes; (void)n_in; (void)out_size; (void)ws_size;
  const int* text = (const int*)d_in[0];
  const float* start_emb = (const float*)d_in[3];
  const float* state_emb = (const float*)d_in[4];
  const float* pre_emb   = (const float*)d_in[5];
  const float* sw1 = (const float*)d_in[6];  const float* sb1 = (const float*)d_in[7];
  const float* sw2 = (const float*)d_in[8];  const float* sb2 = (const float*)d_in[9];
  const float* sw3 = (const float*)d_in[10]; const float* sb3 = (const float*)d_in[11];
  const float* tw1 = (const float*)d_in[12]; const float* tb1 = (const float*)d_in[13];
  const float* tw2 = (const float*)d_in[14]; const float* tb2 = (const float*)d_in[15];
  const float* tw3 = (const float*)d_in[16]; const float* tb3 = (const float*)d_in[17];
  const float* ew1 = (const float*)d_in[18]; const float* eb1 = (const float*)d_in[19];
  const float* ew2 = (const float*)d_in[20]; const float* eb2 = (const float*)d_in[21];
  const float* ew3 = (const float*)d_in[22]; const float* eb3 = (const float*)d_in[23];
  float* out = (float*)d_out;

  char* p = (char*)d_ws;
  auto alloc = [&](size_t bytes) -> char* {
    char* r = p;
    p += (bytes + 255) & ~(size_t)255;
    return r;
  };
  float* slogit = (float*)alloc(C_ * 4);
  float* initv  = (float*)alloc(C_ * 4);
  float* denom  = (float*)alloc(C_ * 4);
  float* LOGZ   = (float*)alloc(N_ * 4);
  float* Pf     = (float*)alloc(C_ * C_ * 4);
  float* PLf    = (float*)alloc(C_ * C_ * 4);
  float* PTf    = (float*)alloc(C_ * C_ * 4);
  _Float16* P_h  = (_Float16*)alloc(C_ * C_ * 2);
  _Float16* PT_h = (_Float16*)alloc(C_ * C_ * 2);
  float* H2    = (float*)alloc(C_ * H_ * 4);
  float* H2T   = (float*)alloc(C_ * H_ * 4);
  float* partm = (float*)alloc(NB_ * C_ * 4);
  float* parts = (float*)alloc(NB_ * C_ * 4);
  float* w3T   = (float*)alloc((size_t)V_ * H_ * 4);
  float* EOBS  = (float*)alloc((size_t)N_ * T_ * C_ * 4);
  float* Karr  = (float*)alloc((size_t)N_ * T_ * 4);
  float* AL    = (float*)alloc((size_t)T_ * N_ * C_ * 4);
  float* BL    = (float*)alloc((size_t)TM1_ * N_ * C_ * 4);
  float* CC    = (float*)alloc((size_t)T_ * N_ * 4);
  float* DD    = (float*)alloc((size_t)TM1_ * N_ * 4);
  _Float16* MtG = (_Float16*)alloc((size_t)2 * N_ * NCH_ * C_ * C_ * 2);
  float* OffG  = (float*)alloc((size_t)2 * N_ * NCH_ * 4);
  float* BND   = (float*)alloc((size_t)2 * N_ * NCH_ * C_ * 4);
  float* BOF   = (float*)alloc((size_t)2 * N_ * NCH_ * 4);

  hipMemsetAsync(d_out, 0, 2 * sizeof(float), stream);

  k_w3t<<<dim3(VT_, H_ / 32), dim3(256), 0, stream>>>(ew3, w3T);
  k_start<<<dim3(C_ / 4), dim3(256), 0, stream>>>(start_emb, sw1, sb1, sw2, sb2, sw3, sb3, slogit);
  k_init<<<dim3(1), dim3(256), 0, stream>>>(slogit, initv);
  k_trans<<<dim3(C_ / 4), dim3(256), 0, stream>>>(state_emb, tw1, tb1, tw2, tb2, tw3, tb3,
                                                  Pf, PLf, PTf, P_h, PT_h);
  k_term_mlp<<<dim3(C_ / 4), dim3(256), 0, stream>>>(pre_emb, ew1, eb1, ew2, eb2, H2, H2T);
  k_term_stats<<<dim3(NB_), dim3(256), 0, stream>>>(H2, ew3, eb3, partm, parts);
  k_denom<<<dim3(1), dim3(256), 0, stream>>>(partm, parts, denom);
  k_obs3<<<dim3(N_ * T_ / 8), dim3(256), 0, stream>>>(text, H2T, w3T, eb3, denom, EOBS, Karr);
  k_chA<<<dim3(15, N_, 2), dim3(256), 0, stream>>>(P_h, PT_h, EOBS, MtG, OffG);
  k_chB<<<dim3(N_, 2), dim3(256), 0, stream>>>(MtG, OffG, initv, EOBS, Karr, BND, BOF);
  k_chC<<<dim3(16, N_, 2), dim3(256), 0, stream>>>(P_h, PT_h, EOBS, Karr, BND, BOF,
                                                   AL, BL, CC, DD, LOGZ);
  k_elbo<<<dim3(TM1_, 2), dim3(256), 0, stream>>>(Pf, PLf, PTf, AL, BL, CC, DD,
                                                  EOBS, Karr, LOGZ, out);
}

// Round 9
// 658.654 us; speedup vs baseline: 1.2512x; 1.2512x over previous
//
#include <hip/hip_runtime.h>
#include <hip/hip_bf16.h>

#define C_ 256
#define H_ 256
#define V_ 10000
#define N_ 8
#define T_ 256
#define TM1_ 255
#define NB_ ((V_ + 31) / 32)
#define VT_ ((V_ + 31) / 32)
#define NCH_ 16                // chunks for the parallel scan
#define MP_ (C_ + 8)           // padded LDS row (f16) -> 132-word stride, no bank conflicts

typedef _Float16 h2_t __attribute__((ext_vector_type(2)));
typedef _Float16 h4_t __attribute__((ext_vector_type(4)));
typedef _Float16 h8_t __attribute__((ext_vector_type(8)));
typedef float f4v __attribute__((ext_vector_type(4)));

// barrier with LDS-only drain (global loads/stores stay in flight)
__device__ __forceinline__ void bar_lgkm() {
  asm volatile("s_waitcnt lgkmcnt(0)\ns_barrier" ::: "memory");
}

__device__ __forceinline__ float wave_red_max(float v) {
#define DPP_MAX(ctrl) { int iv_ = __float_as_int(v); \
  int r_ = __builtin_amdgcn_update_dpp(iv_, iv_, ctrl, 0xF, 0xF, false); \
  v = fmaxf(v, __int_as_float(r_)); }
  DPP_MAX(0x111) DPP_MAX(0x112) DPP_MAX(0x114) DPP_MAX(0x118)
  DPP_MAX(0x142) DPP_MAX(0x143)
#undef DPP_MAX
  return __int_as_float(__builtin_amdgcn_readlane(__float_as_int(v), 63));
}
__device__ __forceinline__ float wave_red_sum(float v) {
#define DPP_ADD(ctrl) { \
  int r_ = __builtin_amdgcn_update_dpp(0, __float_as_int(v), ctrl, 0xF, 0xF, true); \
  v += __int_as_float(r_); }
  DPP_ADD(0x111) DPP_ADD(0x112) DPP_ADD(0x114) DPP_ADD(0x118)
  DPP_ADD(0x142) DPP_ADD(0x143)
#undef DPP_ADD
  return __int_as_float(__builtin_amdgcn_readlane(__float_as_int(v), 63));
}

__device__ __forceinline__ float block_allmax(float v, float* red) {
  v = wave_red_max(v);
  if ((threadIdx.x & 63) == 0) red[threadIdx.x >> 6] = v;
  __syncthreads();
  v = fmaxf(fmaxf(red[0], red[1]), fmaxf(red[2], red[3]));
  __syncthreads();
  return v;
}
__device__ __forceinline__ float block_allsum(float v, float* red) {
  v = wave_red_sum(v);
  if ((threadIdx.x & 63) == 0) red[threadIdx.x >> 6] = v;
  __syncthreads();
  v = (red[0] + red[1]) + (red[2] + red[3]);
  __syncthreads();
  return v;
}

// ---- w3 transpose ----
__global__ __launch_bounds__(256) void k_w3t(const float* __restrict__ w3,
                                             float* __restrict__ w3T) {
  __shared__ float t_s[32][33];
  const int tx = threadIdx.x & 31;
  const int ty = threadIdx.x >> 5;
  const int v0 = blockIdx.x * 32;
  const int k0 = blockIdx.y * 32;
#pragma unroll
  for (int r = 0; r < 4; ++r) {
    int k = k0 + ty + r * 8;
    int v = v0 + tx;
    if (v < V_) t_s[ty + r * 8][tx] = w3[k * V_ + v];
  }
  __syncthreads();
#pragma unroll
  for (int r = 0; r < 4; ++r) {
    int v = v0 + ty + r * 8;
    if (v < V_) w3T[(size_t)v * H_ + k0 + tx] = t_s[tx][ty + r * 8];
  }
}

// ---- residual MLP body ----
__device__ __forceinline__ void mlp4(
    const float* __restrict__ emb,
    const float* __restrict__ w1, const float* __restrict__ b1,
    const float* __restrict__ w2, const float* __restrict__ b2,
    int r0, float (&e_s)[4][C_], float (&h_s)[4][C_], float (&h2_s)[4][C_]) {
  const int tid = threadIdx.x;
#pragma unroll
  for (int rr = 0; rr < 4; ++rr)
    e_s[rr][tid] = emb[(r0 + rr) * H_ + tid];
  __syncthreads();
  float bb = b1[tid];
  float a0 = bb, a1 = bb, a2 = bb, a3 = bb;
  for (int k4 = 0; k4 < H_ / 4; ++k4) {
    float4 e0 = ((const float4*)e_s[0])[k4];
    float4 e1 = ((const float4*)e_s[1])[k4];
    float4 e2 = ((const float4*)e_s[2])[k4];
    float4 e3 = ((const float4*)e_s[3])[k4];
    const float* wp = w1 + (k4 * 4) * H_ + tid;
    float wa = wp[0], wb = wp[H_], wc = wp[2 * H_], wd = wp[3 * H_];
    a0 = fmaf(e0.x, wa, a0); a0 = fmaf(e0.y, wb, a0);
    a0 = fmaf(e0.z, wc, a0); a0 = fmaf(e0.w, wd, a0);
    a1 = fmaf(e1.x, wa, a1); a1 = fmaf(e1.y, wb, a1);
    a1 = fmaf(e1.z, wc, a1); a1 = fmaf(e1.w, wd, a1);
    a2 = fmaf(e2.x, wa, a2); a2 = fmaf(e2.y, wb, a2);
    a2 = fmaf(e2.z, wc, a2); a2 = fmaf(e2.w, wd, a2);
    a3 = fmaf(e3.x, wa, a3); a3 = fmaf(e3.y, wb, a3);
    a3 = fmaf(e3.z, wc, a3); a3 = fmaf(e3.w, wd, a3);
  }
  h_s[0][tid] = fmaxf(a0, 0.f);
  h_s[1][tid] = fmaxf(a1, 0.f);
  h_s[2][tid] = fmaxf(a2, 0.f);
  h_s[3][tid] = fmaxf(a3, 0.f);
  __syncthreads();
  bb = b2[tid];
  a0 = bb; a1 = bb; a2 = bb; a3 = bb;
  for (int k4 = 0; k4 < H_ / 4; ++k4) {
    float4 e0 = ((const float4*)h_s[0])[k4];
    float4 e1 = ((const float4*)h_s[1])[k4];
    float4 e2 = ((const float4*)h_s[2])[k4];
    float4 e3 = ((const float4*)h_s[3])[k4];
    const float* wp = w2 + (k4 * 4) * H_ + tid;
    float wa = wp[0], wb = wp[H_], wc = wp[2 * H_], wd = wp[3 * H_];
    a0 = fmaf(e0.x, wa, a0); a0 = fmaf(e0.y, wb, a0);
    a0 = fmaf(e0.z, wc, a0); a0 = fmaf(e0.w, wd, a0);
    a1 = fmaf(e1.x, wa, a1); a1 = fmaf(e1.y, wb, a1);
    a1 = fmaf(e1.z, wc, a1); a1 = fmaf(e1.w, wd, a1);
    a2 = fmaf(e2.x, wa, a2); a2 = fmaf(e2.y, wb, a2);
    a2 = fmaf(e2.z, wc, a2); a2 = fmaf(e2.w, wd, a2);
    a3 = fmaf(e3.x, wa, a3); a3 = fmaf(e3.y, wb, a3);
    a3 = fmaf(e3.z, wc, a3); a3 = fmaf(e3.w, wd, a3);
  }
  h2_s[0][tid] = fmaxf(a0, 0.f) + e_s[0][tid];
  h2_s[1][tid] = fmaxf(a1, 0.f) + e_s[1][tid];
  h2_s[2][tid] = fmaxf(a2, 0.f) + e_s[2][tid];
  h2_s[3][tid] = fmaxf(a3, 0.f) + e_s[3][tid];
  __syncthreads();
}

__global__ __launch_bounds__(256) void k_start(
    const float* __restrict__ emb, const float* __restrict__ w1,
    const float* __restrict__ b1, const float* __restrict__ w2,
    const float* __restrict__ b2, const float* __restrict__ w3,
    const float* __restrict__ b3, float* __restrict__ slogit) {
  __shared__ __align__(16) float e_s[4][C_], h_s[4][C_], h2_s[4][C_];
  __shared__ float red[4];
  const int r0 = blockIdx.x * 4;
  const int tid = threadIdx.x;
  mlp4(emb, w1, b1, w2, b2, r0, e_s, h_s, h2_s);
  float w3v = w3[tid];
  float s0 = block_allsum(h2_s[0][tid] * w3v, red);
  float s1 = block_allsum(h2_s[1][tid] * w3v, red);
  float s2 = block_allsum(h2_s[2][tid] * w3v, red);
  float s3 = block_allsum(h2_s[3][tid] * w3v, red);
  if (tid == 0) {
    float bb = b3[0];
    slogit[r0 + 0] = s0 + bb;
    slogit[r0 + 1] = s1 + bb;
    slogit[r0 + 2] = s2 + bb;
    slogit[r0 + 3] = s3 + bb;
  }
}

__global__ void k_init(const float* __restrict__ slogit, float* __restrict__ initv) {
  __shared__ float red[4];
  const int tid = threadIdx.x;
  float x = slogit[tid];
  float m = block_allmax(x, red);
  float se = block_allsum(__expf(x - m), red);
  initv[tid] = x - m - __logf(se);
}

__global__ __launch_bounds__(256) void k_trans(
    const float* __restrict__ emb, const float* __restrict__ w1,
    const float* __restrict__ b1, const float* __restrict__ w2,
    const float* __restrict__ b2, const float* __restrict__ w3,
    const float* __restrict__ b3, float* __restrict__ Pf,
    float* __restrict__ PLf, float* __restrict__ PTf,
    _Float16* __restrict__ P_h, _Float16* __restrict__ PT_h) {
  __shared__ __align__(16) float e_s[4][C_], h_s[4][C_], h2_s[4][C_];
  __shared__ float red[4];
  const int r0 = blockIdx.x * 4;
  const int tid = threadIdx.x;
  mlp4(emb, w1, b1, w2, b2, r0, e_s, h_s, h2_s);
  float lb = b3[tid];
  float l0 = lb, l1 = lb, l2 = lb, l3 = lb;
  for (int k4 = 0; k4 < H_ / 4; ++k4) {
    float4 e0 = ((const float4*)h2_s[0])[k4];
    float4 e1 = ((const float4*)h2_s[1])[k4];
    float4 e2 = ((const float4*)h2_s[2])[k4];
    float4 e3 = ((const float4*)h2_s[3])[k4];
    const float* wp = w3 + (k4 * 4) * C_ + tid;
    float wa = wp[0], wb = wp[C_], wc = wp[2 * C_], wd = wp[3 * C_];
    l0 = fmaf(e0.x, wa, l0); l0 = fmaf(e0.y, wb, l0);
    l0 = fmaf(e0.z, wc, l0); l0 = fmaf(e0.w, wd, l0);
    l1 = fmaf(e1.x, wa, l1); l1 = fmaf(e1.y, wb, l1);
    l1 = fmaf(e1.z, wc, l1); l1 = fmaf(e1.w, wd, l1);
    l2 = fmaf(e2.x, wa, l2); l2 = fmaf(e2.y, wb, l2);
    l2 = fmaf(e2.z, wc, l2); l2 = fmaf(e2.w, wd, l2);
    l3 = fmaf(e3.x, wa, l3); l3 = fmaf(e3.y, wb, l3);
    l3 = fmaf(e3.z, wc, l3); l3 = fmaf(e3.w, wd, l3);
  }
  float lg[4] = {l0, l1, l2, l3};
#pragma unroll
  for (int rr = 0; rr < 4; ++rr) {
    float m = block_allmax(lg[rr], red);
    float e = __expf(lg[rr] - m);
    float se = block_allsum(e, red);
    float p = e / se;
    float tv = lg[rr] - m - __logf(se);
    const int r = r0 + rr;
    Pf[r * C_ + tid] = p;
    PLf[r * C_ + tid] = p * tv;
    PTf[tid * C_ + r] = p;
    P_h[r * C_ + tid] = (_Float16)p;
    PT_h[tid * C_ + r] = (_Float16)p;
  }
}

__global__ __launch_bounds__(256) void k_term_mlp(
    const float* __restrict__ emb, const float* __restrict__ w1,
    const float* __restrict__ b1, const float* __restrict__ w2,
    const float* __restrict__ b2, float* __restrict__ H2,
    float* __restrict__ H2T) {
  __shared__ __align__(16) float e_s[4][C_], h_s[4][C_], h2_s[4][C_];
  const int r0 = blockIdx.x * 4;
  const int tid = threadIdx.x;
  mlp4(emb, w1, b1, w2, b2, r0, e_s, h_s, h2_s);
#pragma unroll
  for (int rr = 0; rr < 4; ++rr) {
    const int r = r0 + rr;
    float v = h2_s[rr][tid];
    H2[r * H_ + tid] = v;
    H2T[tid * C_ + r] = v;
  }
}

__global__ __launch_bounds__(256) void k_term_stats(
    const float* __restrict__ H2, const float* __restrict__ w3,
    const float* __restrict__ b3, float* __restrict__ partm,
    float* __restrict__ parts) {
  __shared__ __align__(16) float w3_s[H_][32];
  __shared__ float b3_s[32];
  const int v0 = blockIdx.x * 32;
  const int tid = threadIdx.x;
  const int ncols = min(32, V_ - v0);
  for (int idx = tid; idx < H_ * 32; idx += 256) {
    int k = idx >> 5, c = idx & 31;
    w3_s[k][c] = (c < ncols) ? w3[k * V_ + v0 + c] : 0.f;
  }
  if (tid < 32) b3_s[tid] = (tid < ncols) ? b3[v0 + tid] : 0.f;
  __syncthreads();
  float acc[32];
#pragma unroll
  for (int c = 0; c < 32; ++c) acc[c] = 0.f;
  const float4* hq = (const float4*)(H2 + tid * H_);
  for (int k4 = 0; k4 < H_ / 4; ++k4) {
    float4 h = hq[k4];
    float hk[4];
    *(float4*)hk = h;
#pragma unroll
    for (int kk = 0; kk < 4; ++kk) {
      float hv = hk[kk];
      const int k = k4 * 4 + kk;
      const float4* wq = (const float4*)(&w3_s[k][0]);
#pragma unroll
      for (int c4 = 0; c4 < 8; ++c4) {
        float4 w = wq[c4];
        acc[c4 * 4 + 0] = fmaf(hv, w.x, acc[c4 * 4 + 0]);
        acc[c4 * 4 + 1] = fmaf(hv, w.y, acc[c4 * 4 + 1]);
        acc[c4 * 4 + 2] = fmaf(hv, w.z, acc[c4 * 4 + 2]);
        acc[c4 * 4 + 3] = fmaf(hv, w.w, acc[c4 * 4 + 3]);
      }
    }
  }
  float m = -1e30f;
#pragma unroll
  for (int c = 0; c < 32; ++c) {
    acc[c] += b3_s[c];
    if (c < ncols) m = fmaxf(m, acc[c]);
  }
  float se = 0.f;
#pragma unroll
  for (int c = 0; c < 32; ++c)
    if (c < ncols) se += __expf(acc[c] - m);
  partm[blockIdx.x * C_ + tid] = m;
  parts[blockIdx.x * C_ + tid] = se;
}

__global__ void k_denom(const float* __restrict__ partm,
                        const float* __restrict__ parts,
                        float* __restrict__ denom) {
  const int r = threadIdx.x;
  float m = -1e30f;
#pragma unroll 8
  for (int b = 0; b < NB_; ++b) m = fmaxf(m, partm[b * C_ + r]);
  float s = 0.f;
#pragma unroll 8
  for (int b = 0; b < NB_; ++b)
    s += parts[b * C_ + r] * __expf(partm[b * C_ + r] - m);
  denom[r] = m + __logf(s);
}

// ---- emissions via w3T (coalesced) ----
__global__ __launch_bounds__(256) void k_obs3(
    const int* __restrict__ text, const float* __restrict__ H2T,
    const float* __restrict__ w3T, const float* __restrict__ b3,
    const float* __restrict__ denom, float* __restrict__ EOBS,
    float* __restrict__ Karr) {
  __shared__ __align__(16) float w_s[H_][8];
  __shared__ float redm[4][8];
  const int c = threadIdx.x;
  const int wid = c >> 6;
  const int lane = c & 63;
  const int base = blockIdx.x * 8;
  int tok[8];
#pragma unroll
  for (int i = 0; i < 8; ++i) tok[i] = text[base + i];
  float wtmp[8];
#pragma unroll
  for (int i = 0; i < 8; ++i) wtmp[i] = w3T[(size_t)tok[i] * H_ + c];
  float b3t[8];
#pragma unroll
  for (int i = 0; i < 8; ++i) b3t[i] = b3[tok[i]];
#pragma unroll
  for (int i = 0; i < 8; ++i) w_s[c][i] = wtmp[i];
  __syncthreads();
  float acc[8];
#pragma unroll
  for (int i = 0; i < 8; ++i) acc[i] = 0.f;
  for (int k4 = 0; k4 < H_ / 4; ++k4) {
    float hv[4];
#pragma unroll
    for (int kk = 0; kk < 4; ++kk) hv[kk] = H2T[(k4 * 4 + kk) * C_ + c];
#pragma unroll
    for (int kk = 0; kk < 4; ++kk) {
      const float4* wq = (const float4*)(&w_s[k4 * 4 + kk][0]);
      float4 wa = wq[0], wb = wq[1];
      acc[0] = fmaf(hv[kk], wa.x, acc[0]);
      acc[1] = fmaf(hv[kk], wa.y, acc[1]);
      acc[2] = fmaf(hv[kk], wa.z, acc[2]);
      acc[3] = fmaf(hv[kk], wa.w, acc[3]);
      acc[4] = fmaf(hv[kk], wb.x, acc[4]);
      acc[5] = fmaf(hv[kk], wb.y, acc[5]);
      acc[6] = fmaf(hv[kk], wb.z, acc[6]);
      acc[7] = fmaf(hv[kk], wb.w, acc[7]);
    }
  }
  float dn = denom[c];
  float obsv[8];
#pragma unroll
  for (int i = 0; i < 8; ++i) obsv[i] = acc[i] + b3t[i] - dn;
#pragma unroll
  for (int i = 0; i < 8; ++i) {
    float wm = wave_red_max(obsv[i]);
    if (lane == 0) redm[wid][i] = wm;
  }
  __syncthreads();
#pragma unroll
  for (int i = 0; i < 8; ++i) {
    float Ki = fmaxf(fmaxf(redm[0][i], redm[1][i]),
                     fmaxf(redm[2][i], redm[3][i]));
    EOBS[(base + i) * C_ + c] = __expf(obsv[i] - Ki);
    if (c == 0) Karr[base + i] = Ki;
  }
}

// ============ Phase A: per-chunk matrix products (bank-conflict-free) =======
__global__ __launch_bounds__(256, 1) void k_chA(
    const _Float16* __restrict__ P_h, const _Float16* __restrict__ PT_h,
    const float* __restrict__ EOBS, _Float16* __restrict__ MtG,
    float* __restrict__ OffG) {
  __shared__ __align__(16) _Float16 Mt[C_][MP_];   // 132 KB, padded rows
  __shared__ __align__(16) float eo_s[16][C_];     // 16 KB
  __shared__ float red[4];
  const int j = blockIdx.x;   // chunk 0..14
  const int n = blockIdx.y;
  const int d = blockIdx.z;   // 0 fwd, 1 bwd
  const int tid = threadIdx.x;
  const int wave = tid >> 6, lane = tid & 63, quad = lane >> 4, nn16 = lane & 15;
  for (int i = 0; i < 16; ++i) {
    int e = d ? (255 - 16 * j - i) : (16 * j + 1 + i);
    eo_s[i][tid] = EOBS[((size_t)n * T_ + e) * C_ + tid];
  }
  __syncthreads();
  float lmx = 0.f;
  {
    const _Float16* src = (d ? P_h : PT_h) + (size_t)tid * C_;
    float rowscale = eo_s[0][tid];
    for (int k8 = 0; k8 < 32; ++k8) {
      h8_t v = *(const h8_t*)(src + k8 * 8);
      h8_t o;
#pragma unroll
      for (int q = 0; q < 8; ++q) {
        float f = (float)v[q] * (d ? rowscale : eo_s[0][k8 * 8 + q]);
        lmx = fmaxf(lmx, f);
        o[q] = (_Float16)f;
      }
      *(h8_t*)(&Mt[tid][k8 * 8]) = o;
    }
  }
  {
    float wm = wave_red_max(lmx);
    if (lane == 0) red[wave] = wm;
  }
  bar_lgkm();
  float a = fmaxf(fmaxf(fmaxf(red[0], red[1]), fmaxf(red[2], red[3])), 1e-30f);
  float off = 0.f;
  const _Float16* Ab = d ? PT_h : P_h;
  h8_t afrag[4][8];
#pragma unroll
  for (int mt = 0; mt < 4; ++mt) {
    const _Float16* rp = Ab + (size_t)((wave << 6) + (mt << 4) + nn16) * C_ + (quad << 3);
#pragma unroll
    for (int kt = 0; kt < 8; ++kt) afrag[mt][kt] = *(const h8_t*)(rp + (kt << 5));
  }
#pragma unroll 1
  for (int i = 1; i < 16; ++i) {
    float invs = 1.f / a;
    off += __logf(a);
    lmx = 0.f;
    f4v eoRow[4];
    h8_t eof[8];
    if (!d) {
#pragma unroll
      for (int mt = 0; mt < 4; ++mt)
        eoRow[mt] = *(const f4v*)(&eo_s[i][(wave << 6) + (mt << 4) + (quad << 2)]);
    } else {
#pragma unroll
      for (int kt = 0; kt < 8; ++kt) {
        h8_t t;
#pragma unroll
        for (int q = 0; q < 8; ++q) t[q] = (_Float16)eo_s[i][(kt << 5) + (quad << 3) + q];
        eof[kt] = t;
      }
    }
    // prefetch B-frags for nb=0 (rows 0..15, holding M_{i-1})
    h8_t bfc[8];
#pragma unroll
    for (int kt = 0; kt < 8; ++kt) {
      h8_t raw = *(const h8_t*)(&Mt[nn16][(kt << 5) + (quad << 3)]);
      bfc[kt] = d ? (h8_t)(raw * eof[kt]) : raw;
    }
#pragma unroll 1
    for (int nb = 0; nb < 16; ++nb) {
      f4v acc[4];
#pragma unroll
      for (int mt = 0; mt < 4; ++mt) acc[mt] = (f4v){0.f, 0.f, 0.f, 0.f};
#pragma unroll
      for (int kt = 0; kt < 8; ++kt)
#pragma unroll
        for (int mt = 0; mt < 4; ++mt)
          acc[mt] = __builtin_amdgcn_mfma_f32_16x16x32_f16(afrag[mt][kt], bfc[kt], acc[mt], 0, 0, 0);
      if (nb < 15) {   // prefetch rows nb+1 (old values) before the barrier
#pragma unroll
        for (int kt = 0; kt < 8; ++kt) {
          h8_t raw = *(const h8_t*)(&Mt[((nb + 1) << 4) + nn16][(kt << 5) + (quad << 3)]);
          bfc[kt] = d ? (h8_t)(raw * eof[kt]) : raw;
        }
      }
      h4_t wv[4];
#pragma unroll
      for (int mt = 0; mt < 4; ++mt) {
#pragma unroll
        for (int r = 0; r < 4; ++r) {
          float f = acc[mt][r] * invs * (d ? 1.f : eoRow[mt][r]);
          lmx = fmaxf(lmx, f);
          wv[mt][r] = (_Float16)f;
        }
      }
      bar_lgkm();   // all reads of rows nb (and prefetch nb+1) complete
#pragma unroll
      for (int mt = 0; mt < 4; ++mt)
        *(h4_t*)(&Mt[(nb << 4) + nn16][(wave << 6) + (mt << 4) + (quad << 2)]) = wv[mt];
    }
    float wm = wave_red_max(lmx);
    if (lane == 0) red[wave] = wm;
    bar_lgkm();   // iteration boundary
    a = fmaxf(fmaxf(fmaxf(red[0], red[1]), fmaxf(red[2], red[3])), 1e-30f);
  }
  // copy out (unpadded global layout)
  _Float16* dst = MtG + (((size_t)d * 8 + n) * NCH_ + j) * (C_ * C_);
  h8_t* d8 = (h8_t*)dst;
  for (int i2 = 0; i2 < 32; ++i2) {
    int f = i2 * 256 + tid;
    int row = f >> 5, c8 = f & 31;
    d8[f] = *(const h8_t*)(&Mt[row][c8 * 8]);
  }
  if (tid == 0) OffG[((size_t)d * 8 + n) * NCH_ + j] = off;
}

// ============ Phase B: boundary vectors (512 threads, split-k) =============
__global__ __launch_bounds__(512) void k_chB(
    const _Float16* __restrict__ MtG, const float* __restrict__ OffG,
    const float* __restrict__ initv, const float* __restrict__ EOBS,
    const float* __restrict__ Karr, float* __restrict__ BND,
    float* __restrict__ BOF) {
  __shared__ float b_s[C_];
  __shared__ float part[C_];
  __shared__ float red[8];
  __shared__ float Ksum[16];
  const int n = blockIdx.x, d = blockIdx.y;
  const int tid = threadIdx.x;
  const int c = tid & 255;
  const int half = tid >> 8;
  const int wv8 = tid >> 6;
  const int lane = tid & 63;
  if (tid < 15) {
    float ks = 0.f;
    for (int i = 0; i < 16; ++i) {
      int e = d ? (255 - 16 * tid - i) : (16 * tid + 1 + i);
      ks += Karr[n * T_ + e];
    }
    Ksum[tid] = ks;
  }
  float b = 1.f, boff = 0.f;
  if (d == 0) {
    float x0 = initv[c] + __logf(EOBS[(size_t)(n * T_) * C_ + c]) + Karr[n * T_];
    float wm = wave_red_max(x0);
    if (lane == 0) red[wv8] = wm;
    __syncthreads();
    float m0 = red[0];
#pragma unroll
    for (int w = 1; w < 8; ++w) m0 = fmaxf(m0, red[w]);
    b = __expf(x0 - m0);
    boff = m0;
  }
  const size_t base = ((size_t)d * 8 + n) * NCH_;
  if (half == 0) {
    BND[(base + 0) * C_ + c] = b;
    if (tid == 0) BOF[base + 0] = boff;
  }
#pragma unroll 1
  for (int j = 0; j < 15; ++j) {
    if (half == 0) b_s[c] = b;
    __syncthreads();
    const _Float16* M = MtG + (base + j) * (C_ * C_) + (size_t)half * 128 * C_;
    const float* bh = b_s + half * 128;
    float acc = 0.f;
#pragma unroll 1
    for (int k = 0; k < 128; k += 8) {
      float m0v = (float)M[(size_t)(k + 0) * C_ + c];
      float m1v = (float)M[(size_t)(k + 1) * C_ + c];
      float m2v = (float)M[(size_t)(k + 2) * C_ + c];
      float m3v = (float)M[(size_t)(k + 3) * C_ + c];
      float m4v = (float)M[(size_t)(k + 4) * C_ + c];
      float m5v = (float)M[(size_t)(k + 5) * C_ + c];
      float m6v = (float)M[(size_t)(k + 6) * C_ + c];
      float m7v = (float)M[(size_t)(k + 7) * C_ + c];
      acc = fmaf(m0v, bh[k + 0], acc);
      acc = fmaf(m1v, bh[k + 1], acc);
      acc = fmaf(m2v, bh[k + 2], acc);
      acc = fmaf(m3v, bh[k + 3], acc);
      acc = fmaf(m4v, bh[k + 4], acc);
      acc = fmaf(m5v, bh[k + 5], acc);
      acc = fmaf(m6v, bh[k + 6], acc);
      acc = fmaf(m7v, bh[k + 7], acc);
    }
    if (half == 1) part[c] = acc;
    __syncthreads();
    float tval = 0.f;
    if (half == 0) {
      tval = acc + part[c];
      float wm = wave_red_max(tval);
      if (lane == 0) red[wv8] = wm;
    }
    __syncthreads();
    float m = fmaxf(fmaxf(fmaxf(red[0], red[1]), fmaxf(red[2], red[3])), 1e-30f);
    boff += OffG[base + j] + __logf(m) + Ksum[j];
    if (half == 0) {
      b = tval / m;
      BND[(base + j + 1) * C_ + c] = b;
      if (tid == 0) BOF[base + j + 1] = boff;
    }
  }
}

// ============ Phase C: within-chunk replay (proven MFMA matvec) =============
__global__ __launch_bounds__(256, 1) void k_chC(
    const _Float16* __restrict__ P_h, const _Float16* __restrict__ PT_h,
    const float* __restrict__ EOBS, const float* __restrict__ Karr,
    const float* __restrict__ BND, const float* __restrict__ BOF,
    float* __restrict__ AL, float* __restrict__ BL, float* __restrict__ CC,
    float* __restrict__ DD, float* __restrict__ LOGZ) {
  __shared__ __align__(16) _Float16 ubuf[C_];
  __shared__ __align__(16) float eo_s[16][C_];
  __shared__ float Ksm[16];
  __shared__ float red[4];
  const int j = blockIdx.x;   // 0..15
  const int n = blockIdx.y;
  const int d = blockIdx.z;
  const int tid = threadIdx.x;
  const int wave = tid >> 6, lane = tid & 63, quad = lane >> 4, nn16 = lane & 15;
  const int len = d ? ((j == 15) ? 14 : 16) : ((j == 15) ? 15 : 16);
  for (int i = 0; i < len; ++i) {
    int e = d ? (255 - 16 * j - i) : (16 * j + 1 + i);
    eo_s[i][tid] = EOBS[((size_t)n * T_ + e) * C_ + tid];
  }
  if (tid < len) {
    int e = d ? (255 - 16 * j - tid) : (16 * j + 1 + tid);
    Ksm[tid] = Karr[n * T_ + e];
  }
  const _Float16* M = d ? PT_h : P_h;
  h8_t afrag[4][8];
#pragma unroll
  for (int mt = 0; mt < 4; ++mt) {
    const _Float16* rp = M + (size_t)((wave << 6) + (mt << 4) + nn16) * C_ + (quad << 3);
#pragma unroll
    for (int kt = 0; kt < 8; ++kt) afrag[mt][kt] = *(const h8_t*)(rp + (kt << 5));
  }
  const int stb = (wave << 6) + (quad << 2);
  const size_t base = ((size_t)d * 8 + n) * NCH_ + j;
  f4v v[4];
  {
    const float* bp = BND + base * C_;
#pragma unroll
    for (int mt = 0; mt < 4; ++mt) v[mt] = *(const f4v*)(bp + stb + (mt << 4));
  }
  float off = BOF[base];
  __syncthreads();

  if (d == 0) {
    if (j == 0) {
      if (nn16 == 0) {
#pragma unroll
        for (int mt = 0; mt < 4; ++mt)
          *(f4v*)(AL + (size_t)(0 * N_ + n) * C_ + stb + (mt << 4)) = v[mt];
      }
      if (tid == 0) CC[0 * N_ + n] = off;
    }
    if (nn16 == 0) {
#pragma unroll
      for (int mt = 0; mt < 4; ++mt) {
        h4_t p;
#pragma unroll
        for (int r = 0; r < 4; ++r) p[r] = (_Float16)v[mt][r];
        *(h4_t*)(&ubuf[stb + (mt << 4)]) = p;
      }
    }
    bar_lgkm();
#pragma unroll 1
    for (int i = 0; i < len; ++i) {
      const int e = 16 * j + 1 + i;
      h8_t bf[8];
#pragma unroll
      for (int kt = 0; kt < 8; ++kt)
        bf[kt] = *(const h8_t*)(&ubuf[(kt << 5) + (quad << 3)]);
      f4v acc[4];
#pragma unroll
      for (int mt = 0; mt < 4; ++mt) acc[mt] = (f4v){0.f, 0.f, 0.f, 0.f};
#pragma unroll
      for (int kt = 0; kt < 8; ++kt)
#pragma unroll
        for (int mt = 0; mt < 4; ++mt)
          acc[mt] = __builtin_amdgcn_mfma_f32_16x16x32_f16(afrag[mt][kt], bf[kt], acc[mt], 0, 0, 0);
      float lmx = -1e30f;
#pragma unroll
      for (int mt = 0; mt < 4; ++mt) {
        f4v eoR = *(const f4v*)(&eo_s[i][stb + (mt << 4)]);
#pragma unroll
        for (int r = 0; r < 4; ++r) {
          v[mt][r] = acc[mt][r] * eoR[r];
          lmx = fmaxf(lmx, v[mt][r]);
        }
      }
      float wm = wave_red_max(lmx);
      if (lane == 0) red[wave] = wm;
      bar_lgkm();
      float m = fmaxf(fmaxf(fmaxf(red[0], red[1]), fmaxf(red[2], red[3])), 1e-30f);
      float invm = 1.f / m;
      off += Ksm[i] + __logf(m);
#pragma unroll
      for (int mt = 0; mt < 4; ++mt)
#pragma unroll
        for (int r = 0; r < 4; ++r) v[mt][r] *= invm;
      if (nn16 == 0) {
#pragma unroll
        for (int mt = 0; mt < 4; ++mt) {
          h4_t p;
#pragma unroll
          for (int r = 0; r < 4; ++r) p[r] = (_Float16)v[mt][r];
          *(h4_t*)(&ubuf[stb + (mt << 4)]) = p;
          *(f4v*)(AL + (size_t)(e * N_ + n) * C_ + stb + (mt << 4)) = v[mt];
        }
      }
      if (tid == 0) CC[e * N_ + n] = off;
      bar_lgkm();
    }
    if (j == 15) {
      float s = 0.f;
#pragma unroll
      for (int mt = 0; mt < 4; ++mt)
        s += (v[mt][0] + v[mt][1]) + (v[mt][2] + v[mt][3]);
      s = wave_red_sum(s);
      if (lane == 0) red[wave] = s;
      __syncthreads();
      if (tid == 0) {
        float S = ((red[0] + red[1]) + (red[2] + red[3])) * (1.f / 16.f);
        LOGZ[n] = __logf(S) + off;
      }
    }
  } else {
    if (j == 0) {
      if (nn16 == 0) {
        f4v one = (f4v){1.f, 1.f, 1.f, 1.f};
#pragma unroll
        for (int mt = 0; mt < 4; ++mt)
          *(f4v*)(BL + (size_t)(254 * N_ + n) * C_ + stb + (mt << 4)) = one;
      }
      if (tid == 0) DD[254 * N_ + n] = 0.f;
    }
#pragma unroll 1
    for (int i = 0; i < len; ++i) {
      const int t = 253 - 16 * j - i;
      if (nn16 == 0) {
#pragma unroll
        for (int mt = 0; mt < 4; ++mt) {
          f4v eoR = *(const f4v*)(&eo_s[i][stb + (mt << 4)]);
          h4_t p;
#pragma unroll
          for (int r = 0; r < 4; ++r) p[r] = (_Float16)(v[mt][r] * eoR[r]);
          *(h4_t*)(&ubuf[stb + (mt << 4)]) = p;
        }
      }
      bar_lgkm();
      h8_t bf[8];
#pragma unroll
      for (int kt = 0; kt < 8; ++kt)
        bf[kt] = *(const h8_t*)(&ubuf[(kt << 5) + (quad << 3)]);
      f4v acc[4];
#pragma unroll
      for (int mt = 0; mt < 4; ++mt) acc[mt] = (f4v){0.f, 0.f, 0.f, 0.f};
#pragma unroll
      for (int kt = 0; kt < 8; ++kt)
#pragma unroll
        for (int mt = 0; mt < 4; ++mt)
          acc[mt] = __builtin_amdgcn_mfma_f32_16x16x32_f16(afrag[mt][kt], bf[kt], acc[mt], 0, 0, 0);
      float lmx = -1e30f;
#pragma unroll
      for (int mt = 0; mt < 4; ++mt)
#pragma unroll
        for (int r = 0; r < 4; ++r) lmx = fmaxf(lmx, acc[mt][r]);
      float wm = wave_red_max(lmx);
      if (lane == 0) red[wave] = wm;
      bar_lgkm();
      float m = fmaxf(fmaxf(fmaxf(red[0], red[1]), fmaxf(red[2], red[3])), 1e-30f);
      float invm = 1.f / m;
      off += Ksm[i] + __logf(m);
#pragma unroll
      for (int mt = 0; mt < 4; ++mt) {
#pragma unroll
        for (int r = 0; r < 4; ++r) v[mt][r] = acc[mt][r] * invm;
        if (nn16 == 0)
          *(f4v*)(BL + (size_t)(t * N_ + n) * C_ + stb + (mt << 4)) = v[mt];
      }
      if (tid == 0) DD[t * N_ + n] = off;
    }
  }
}

// ---- elbo, split over 2 sequence groups (+ fused evidence) ----
#define NH_ 4
__global__ __launch_bounds__(256) void k_elbo(
    const float* __restrict__ Pf, const float* __restrict__ PLf,
    const float* __restrict__ PTf, const float* __restrict__ AL,
    const float* __restrict__ BL, const float* __restrict__ CC,
    const float* __restrict__ DD, const float* __restrict__ EOBS,
    const float* __restrict__ Karr, const float* __restrict__ LOGZ,
    float* __restrict__ out) {
  __shared__ __align__(16) float A_s[NH_][C_];
  __shared__ __align__(16) float B_s[NH_][C_];
  __shared__ float red[4];
  const int t = blockIdx.x;
  const int nb = blockIdx.y * NH_;
  const int c = threadIdx.x;
  if (t == 0 && blockIdx.y == 0 && c == 0) {
    float s = 0.f;
#pragma unroll
    for (int nn = 0; nn < N_; ++nn) s += LOGZ[nn];
    out[1] = s;
  }
  float sc[NH_], Kv[NH_], cc[NH_];
#pragma unroll
  for (int nn = 0; nn < NH_; ++nn) {
    const int n = nb + nn;
    A_s[nn][c] = AL[(t * N_ + n) * C_ + c];
    Kv[nn] = Karr[n * T_ + t + 1];
    cc[nn] = CC[t * N_ + n];
    sc[nn] = __expf(cc[nn] + DD[t * N_ + n] + Kv[nn] - LOGZ[n]);
  }
  __syncthreads();
  float accPA[NH_], accPL[NH_];
#pragma unroll
  for (int nn = 0; nn < NH_; ++nn) { accPA[nn] = 0.f; accPL[nn] = 0.f; }
  const float4* pr = (const float4*)(Pf + c * C_);
  const float4* plr = (const float4*)(PLf + c * C_);
  for (int jj = 0; jj < C_ / 4; ++jj) {
    float4 p = pr[jj];
    float4 pl = plr[jj];
#pragma unroll
    for (int nn = 0; nn < NH_; ++nn) {
      float4 a = ((const float4*)A_s[nn])[jj];
      accPA[nn] += p.x * a.x + p.y * a.y + p.z * a.z + p.w * a.w;
      accPL[nn] += pl.x * a.x + pl.y * a.y + pl.z * a.z + pl.w * a.w;
    }
  }
  float contrib = 0.f;
  float Bv[NH_];
#pragma unroll
  for (int nn = 0; nn < NH_; ++nn) {
    const int n = nb + nn;
    float eo = EOBS[(n * T_ + t + 1) * C_ + c];
    float ob = __logf(eo) + Kv[nn];
    float B = eo * BL[(t * N_ + n) * C_ + c] * sc[nn];
    Bv[nn] = B;
    contrib += B * fmaf(ob, accPA[nn], accPL[nn]);
  }
  if (t == 0) {
#pragma unroll
    for (int nn = 0; nn < NH_; ++nn) B_s[nn][c] = Bv[nn];
    __syncthreads();
    const float4* ptq = (const float4*)(PTf + c * C_);
    float accPT[NH_];
#pragma unroll
    for (int nn = 0; nn < NH_; ++nn) accPT[nn] = 0.f;
    for (int jj = 0; jj < C_ / 4; ++jj) {
      float4 p = ptq[jj];
#pragma unroll
      for (int nn = 0; nn < NH_; ++nn) {
        float4 b = ((const float4*)B_s[nn])[jj];
        accPT[nn] += p.x * b.x + p.y * b.y + p.z * b.z + p.w * b.w;
      }
    }
#pragma unroll
    for (int nn = 0; nn < NH_; ++nn) {
      float a0v = A_s[nn][c];
      if (a0v > 0.f)
        contrib += a0v * (__logf(a0v) + cc[nn]) * accPT[nn];
    }
  }
  contrib = wave_red_sum(contrib);
  if ((c & 63) == 0) red[c >> 6] = contrib;
  __syncthreads();
  if (c == 0) atomicAdd(out, (red[0] + red[1]) + (red[2] + red[3]));
}

extern "C" void kernel_launch(void* const* d_in, const int* in_sizes, int n_in,
                              void* d_out, int out_size, void* d_ws, size_t ws_size,
                              hipStream_t stream) {
  (void)in_sizes; (void)n_in; (void)out_size; (void)ws_size;
  const int* text = (const int*)d_in[0];
  const float* start_emb = (const float*)d_in[3];
  const float* state_emb = (const float*)d_in[4];
  const float* pre_emb   = (const float*)d_in[5];
  const float* sw1 = (const float*)d_in[6];  const float* sb1 = (const float*)d_in[7];
  const float* sw2 = (const float*)d_in[8];  const float* sb2 = (const float*)d_in[9];
  const float* sw3 = (const float*)d_in[10]; const float* sb3 = (const float*)d_in[11];
  const float* tw1 = (const float*)d_in[12]; const float* tb1 = (const float*)d_in[13];
  const float* tw2 = (const float*)d_in[14]; const float* tb2 = (const float*)d_in[15];
  const float* tw3 = (const float*)d_in[16]; const float* tb3 = (const float*)d_in[17];
  const float* ew1 = (const float*)d_in[18]; const float* eb1 = (const float*)d_in[19];
  const float* ew2 = (const float*)d_in[20]; const float* eb2 = (const float*)d_in[21];
  const float* ew3 = (const float*)d_in[22]; const float* eb3 = (const float*)d_in[23];
  float* out = (float*)d_out;

  char* p = (char*)d_ws;
  auto alloc = [&](size_t bytes) -> char* {
    char* r = p;
    p += (bytes + 255) & ~(size_t)255;
    return r;
  };
  float* slogit = (float*)alloc(C_ * 4);
  float* initv  = (float*)alloc(C_ * 4);
  float* denom  = (float*)alloc(C_ * 4);
  float* LOGZ   = (float*)alloc(N_ * 4);
  float* Pf     = (float*)alloc(C_ * C_ * 4);
  float* PLf    = (float*)alloc(C_ * C_ * 4);
  float* PTf    = (float*)alloc(C_ * C_ * 4);
  _Float16* P_h  = (_Float16*)alloc(C_ * C_ * 2);
  _Float16* PT_h = (_Float16*)alloc(C_ * C_ * 2);
  float* H2    = (float*)alloc(C_ * H_ * 4);
  float* H2T   = (float*)alloc(C_ * H_ * 4);
  float* partm = (float*)alloc(NB_ * C_ * 4);
  float* parts = (float*)alloc(NB_ * C_ * 4);
  float* w3T   = (float*)alloc((size_t)V_ * H_ * 4);
  float* EOBS  = (float*)alloc((size_t)N_ * T_ * C_ * 4);
  float* Karr  = (float*)alloc((size_t)N_ * T_ * 4);
  float* AL    = (float*)alloc((size_t)T_ * N_ * C_ * 4);
  float* BL    = (float*)alloc((size_t)TM1_ * N_ * C_ * 4);
  float* CC    = (float*)alloc((size_t)T_ * N_ * 4);
  float* DD    = (float*)alloc((size_t)TM1_ * N_ * 4);
  _Float16* MtG = (_Float16*)alloc((size_t)2 * N_ * NCH_ * C_ * C_ * 2);
  float* OffG  = (float*)alloc((size_t)2 * N_ * NCH_ * 4);
  float* BND   = (float*)alloc((size_t)2 * N_ * NCH_ * C_ * 4);
  float* BOF   = (float*)alloc((size_t)2 * N_ * NCH_ * 4);

  hipMemsetAsync(d_out, 0, 2 * sizeof(float), stream);

  k_w3t<<<dim3(VT_, H_ / 32), dim3(256), 0, stream>>>(ew3, w3T);
  k_start<<<dim3(C_ / 4), dim3(256), 0, stream>>>(start_emb, sw1, sb1, sw2, sb2, sw3, sb3, slogit);
  k_init<<<dim3(1), dim3(256), 0, stream>>>(slogit, initv);
  k_trans<<<dim3(C_ / 4), dim3(256), 0, stream>>>(state_emb, tw1, tb1, tw2, tb2, tw3, tb3,
                                                  Pf, PLf, PTf, P_h, PT_h);
  k_term_mlp<<<dim3(C_ / 4), dim3(256), 0, stream>>>(pre_emb, ew1, eb1, ew2, eb2, H2, H2T);
  k_term_stats<<<dim3(NB_), dim3(256), 0, stream>>>(H2, ew3, eb3, partm, parts);
  k_denom<<<dim3(1), dim3(256), 0, stream>>>(partm, parts, denom);
  k_obs3<<<dim3(N_ * T_ / 8), dim3(256), 0, stream>>>(text, H2T, w3T, eb3, denom, EOBS, Karr);
  k_chA<<<dim3(15, N_, 2), dim3(256), 0, stream>>>(P_h, PT_h, EOBS, MtG, OffG);
  k_chB<<<dim3(N_, 2), dim3(512), 0, stream>>>(MtG, OffG, initv, EOBS, Karr, BND, BOF);
  k_chC<<<dim3(16, N_, 2), dim3(256), 0, stream>>>(P_h, PT_h, EOBS, Karr, BND, BOF,
                                                   AL, BL, CC, DD, LOGZ);
  k_elbo<<<dim3(TM1_, 2), dim3(256), 0, stream>>>(Pf, PLf, PTf, AL, BL, CC, DD,
                                                  EOBS, Karr, LOGZ, out);
}